// Round 12
// baseline (313.817 us; speedup 1.0000x reference)
//
#include <hip/hip_runtime.h>
#include <hip/hip_bf16.h>

// AttnBlock: B=8, C=512, N=2048, G=32.
// All GEMMs NT: Out[m][n] = sum_k A[m][k] * Bt[n][k].
// gemm12<MODE>: LDS-read-ratio fix. 256x128 tile, 8 waves (4Mx2N, wave 64x64).
//   A: LDS 2-slot (64KB), swizzled, staged 1 tile ahead (global_load_lds),
//      counted gate WAITVM(8) at tile top (leaves the 8 direct-B loads in flight).
//   B: DIRECT global->VGPR per wave (bf[4][2] short8), issued at end of prev tile;
//      compiler inserts the counted vmcnt before first MFMA use.
//   Per-CU per-tile: LDS reads 64KB (753cy) < MFMA 904cy -> MFMA-bound (was 128-192KB).
// Batch->XCD pinning kept. 16x16x32 MFMA (proven layout). 1 barrier/tile.

typedef __attribute__((ext_vector_type(8))) short short8;
typedef __attribute__((ext_vector_type(4))) float f32x4;
typedef unsigned short u16;

#define WAITVM(N) asm volatile("s_waitcnt vmcnt(" #N ")" ::: "memory")
#define LGKM0 asm volatile("s_waitcnt lgkmcnt(0)" ::: "memory")
#define SCB __builtin_amdgcn_sched_barrier(0)

__device__ __forceinline__ u16 f2bf(float f) {
  __hip_bfloat16 h = __float2bfloat16(f);
  return __builtin_bit_cast(u16, h);
}
__device__ __forceinline__ float bf2f(u16 u) {
  return __uint_as_float(((unsigned)u) << 16);
}

__device__ __forceinline__ void gload_lds16(const void* g, void* l) {
  __builtin_amdgcn_global_load_lds((const __attribute__((address_space(1))) void*)g,
                                   (__attribute__((address_space(3))) void*)l, 16, 0, 0);
}

// MODE 0: bf16 out = acc + bias[col]   MODE 1: + bias[row]   MODE 2: * scale
// MODE 3: raw bf16                     MODE 4: f32 + bias[row] + resid
// Grid: 1-D, gid = t*8 + b;  t = by*GX + bx;  m0 = by*256 + b*mOffB; n0 = bx*128.
template <int MODE>
__global__ __launch_bounds__(512) void gemm12(
    const u16* __restrict__ A, const u16* __restrict__ Bt, void* __restrict__ OutV,
    const float* __restrict__ bias, const float* __restrict__ resid,
    int K, int lda, int ldb, int ldo, int GX, int mOffB,
    long sA, long sBt, long sOut, long sRes, float scale) {
  constexpr int A_EL = 256 * 64;  // one A slot: 32 KB

  __shared__ __align__(16) u16 lds[2 * A_EL];  // 64 KB

  const int gid = blockIdx.x;
  const int b = gid & 7;  // batch == XCD (round-robin dispatch)
  const int t0 = gid >> 3;
  const int bx = t0 % GX;
  const int by = t0 / GX;
  const u16* Ab = A + (long)b * sA;
  const u16* Bb = Bt + (long)b * sBt;
  const int tid = threadIdx.x;
  const int lane = tid & 63;
  const int wid = tid >> 6;
  const int wr = wid >> 1;  // 0..3 (M groups of 64)
  const int wc = wid & 1;   // 0..1 (N groups of 64)
  const int m0 = by * 256 + b * mOffB;
  const int n0 = bx * 128;
  const int l15 = lane & 15;
  const int lhi = lane >> 4;

  f32x4 acc[4][4];
#pragma unroll
  for (int i = 0; i < 4; ++i)
#pragma unroll
    for (int j = 0; j < 4; ++j) acc[i][j] = (f32x4){0.f, 0.f, 0.f, 0.f};

  const int T = K / 64;

  // stage A K-tile kt (256x64 bf16 = 32KB) into slot kt&1, swizzled 16B slots
  auto stage = [&](int kt) {
    u16* As = lds + (size_t)(kt & 1) * A_EL;
#pragma unroll
    for (int i = 0; i < 4; ++i) {
      const int c = tid + i * 512;   // 0..2047
      const int row = c >> 3;        // 0..255
      const int slot = (c & 7) ^ (row & 7);
      gload_lds16(Ab + (long)(m0 + row) * lda + kt * 64 + slot * 8, (void*)(As + c * 8));
    }
  };

  // direct global->reg B fragments for K-tile kt: bf[nf][kh]
  short8 bf[4][2];
  auto ldB = [&](int kt) {
#pragma unroll
    for (int nf = 0; nf < 4; ++nf)
#pragma unroll
      for (int kh = 0; kh < 2; ++kh)
        bf[nf][kh] = *(const short8*)(Bb + (long)(n0 + wc * 64 + nf * 16 + l15) * ldb +
                                      kt * 64 + kh * 32 + lhi * 8);
  };

  stage(0);
  ldB(0);

  for (int t = 0; t < T; ++t) {
    // A(t) staged one tile ago; 8 youngest outstanding = this tile's bf (compiler-gated)
    WAITVM(8);
    SCB;
    __builtin_amdgcn_s_barrier();
    SCB;
    if (t + 1 < T) stage(t + 1);  // other slot; its t-1 readers all passed this barrier

    const u16* A_ = lds + (size_t)(t & 1) * A_EL;
    short8 af0[4], af1[4];
#pragma unroll
    for (int mf = 0; mf < 4; ++mf)
      af0[mf] = *(const short8*)(A_ + (wr * 64 + mf * 16 + l15) * 64 +
                                 ((0 * 4 + lhi) ^ (l15 & 7)) * 8);
    LGKM0; SCB;
#pragma unroll
    for (int mf = 0; mf < 4; ++mf)
      af1[mf] = *(const short8*)(A_ + (wr * 64 + mf * 16 + l15) * 64 +
                                 ((1 * 4 + lhi) ^ (l15 & 7)) * 8);
    SCB;
    __builtin_amdgcn_s_setprio(1);
#pragma unroll
    for (int mf = 0; mf < 4; ++mf)
#pragma unroll
      for (int nf = 0; nf < 4; ++nf)
        acc[mf][nf] = __builtin_amdgcn_mfma_f32_16x16x32_bf16(af0[mf], bf[nf][0], acc[mf][nf], 0, 0, 0);
    __builtin_amdgcn_s_setprio(0);
    LGKM0; SCB;
    __builtin_amdgcn_s_setprio(1);
#pragma unroll
    for (int mf = 0; mf < 4; ++mf)
#pragma unroll
      for (int nf = 0; nf < 4; ++nf)
        acc[mf][nf] = __builtin_amdgcn_mfma_f32_16x16x32_bf16(af1[mf], bf[nf][1], acc[mf][nf], 0, 0, 0);
    __builtin_amdgcn_s_setprio(0);
    SCB;
    if (t + 1 < T) ldB(t + 1);  // overwrite bf after all MFMA of t; lands during t+1 top
  }

  // epilogue: D row=(lane>>4)*4+reg (m), col=lane&15 (n); plain stores (L2-merged)
  const int rbase = m0 + wr * 64 + lhi * 4;
  const int cbase = n0 + wc * 64 + l15;
#pragma unroll
  for (int mf = 0; mf < 4; ++mf) {
#pragma unroll
    for (int nf = 0; nf < 4; ++nf) {
#pragma unroll
      for (int i = 0; i < 4; ++i) {
        const int row = rbase + mf * 16 + i;
        const int col = cbase + nf * 16;
        const long oidx = (long)b * sOut + (long)row * ldo + col;
        const float v = acc[mf][nf][i];
        if (MODE == 0) {
          ((u16*)OutV)[oidx] = f2bf(v + bias[col]);
        } else if (MODE == 1) {
          ((u16*)OutV)[oidx] = f2bf(v + bias[row]);
        } else if (MODE == 2) {
          ((u16*)OutV)[oidx] = f2bf(v * scale);
        } else if (MODE == 3) {
          ((u16*)OutV)[oidx] = f2bf(v);
        } else {
          const float r = resid[(long)b * sRes + (long)row * ldo + col];
          ((float*)OutV)[oidx] = v + bias[row] + r;
        }
      }
    }
  }
}

// per-(b,g) mean/rstd over contiguous 16*2048 = 32768 floats
__global__ __launch_bounds__(256) void gn_stats(const float* __restrict__ x,
                                                float* __restrict__ stats) {
  const int bg = blockIdx.x;
  const float4* p4 = (const float4*)(x + (long)bg * 32768);
  float s = 0.f, ss = 0.f;
  for (int i = threadIdx.x; i < 8192; i += 256) {
    const float4 u = p4[i];
    s += (u.x + u.y) + (u.z + u.w);
    ss += (u.x * u.x + u.y * u.y) + (u.z * u.z + u.w * u.w);
  }
#pragma unroll
  for (int off = 32; off > 0; off >>= 1) {
    s += __shfl_xor(s, off, 64);
    ss += __shfl_xor(ss, off, 64);
  }
  __shared__ float rs[4], rss[4];
  const int lane = threadIdx.x & 63, wid = threadIdx.x >> 6;
  if (lane == 0) { rs[wid] = s; rss[wid] = ss; }
  __syncthreads();
  if (threadIdx.x == 0) {
    s = rs[0] + rs[1] + rs[2] + rs[3];
    ss = rss[0] + rss[1] + rss[2] + rss[3];
    const float mean = s * (1.f / 32768.f);
    const float var = ss * (1.f / 32768.f) - mean * mean;
    stats[bg * 2] = mean;
    stats[bg * 2 + 1] = rsqrtf(var + 1e-6f);
  }
}

// normalize + affine, write hT[b][n][c] bf16 (64x64 LDS-tiled transpose)
__global__ __launch_bounds__(256) void gn_apply_t(
    const float* __restrict__ x, const float* __restrict__ stats,
    const float* __restrict__ gamma, const float* __restrict__ beta,
    u16* __restrict__ hT) {
  const int b = blockIdx.z, c0 = blockIdx.y * 64, n0 = blockIdx.x * 64;
  __shared__ u16 t[64][72];
  const int tid = threadIdx.x;
  const float* px = x + ((long)b * 512 + c0) * 2048 + n0;
#pragma unroll
  for (int i = 0; i < 4; ++i) {
    const int idx = tid + i * 256;
    const int r = idx >> 4, q4 = (idx & 15) * 4;
    const float4 u = *(const float4*)(px + (long)r * 2048 + q4);
    const int c = c0 + r, g = c >> 4;
    const float mean = stats[(b * 32 + g) * 2];
    const float rstd = stats[(b * 32 + g) * 2 + 1];
    const float ga = gamma[c] * rstd;
    const float be = beta[c] - mean * ga;
    t[r][q4 + 0] = f2bf(u.x * ga + be);
    t[r][q4 + 1] = f2bf(u.y * ga + be);
    t[r][q4 + 2] = f2bf(u.z * ga + be);
    t[r][q4 + 3] = f2bf(u.w * ga + be);
  }
  __syncthreads();
#pragma unroll
  for (int i = 0; i < 2; ++i) {
    const int idx = tid + i * 256;
    const int nr = idx >> 3, cc = (idx & 7) * 8;
    short8 w;
#pragma unroll
    for (int j = 0; j < 8; ++j) w[j] = (short)t[cc + j][nr];
    *(short8*)(hT + ((long)b * 2048 + n0 + nr) * 512 + c0 + cc) = w;
  }
}

// row softmax in place on bf16 S; gid = r*8 + b, row = b*2048 + r (XCD-pinned)
__global__ __launch_bounds__(256) void softmax_rows(u16* __restrict__ S) {
  const int gid = blockIdx.x;
  const long row = (long)(gid & 7) * 2048 + (gid >> 3);
  u16* p = S + row * 2048;
  const int tid = threadIdx.x;
  const int lane = tid & 63, wid = tid >> 6;
  const short8 raw = *(const short8*)(p + tid * 8);
  float v[8];
#pragma unroll
  for (int j = 0; j < 8; ++j) v[j] = bf2f((u16)raw[j]);
  float m = v[0];
#pragma unroll
  for (int j = 1; j < 8; ++j) m = fmaxf(m, v[j]);
#pragma unroll
  for (int off = 32; off > 0; off >>= 1) m = fmaxf(m, __shfl_xor(m, off, 64));
  __shared__ float redm[4], reds[4];
  if (lane == 0) redm[wid] = m;
  __syncthreads();
  m = fmaxf(fmaxf(redm[0], redm[1]), fmaxf(redm[2], redm[3]));
  float e[8];
  float s = 0.f;
#pragma unroll
  for (int j = 0; j < 8; ++j) {
    e[j] = __expf(v[j] - m);
    s += e[j];
  }
#pragma unroll
  for (int off = 32; off > 0; off >>= 1) s += __shfl_xor(s, off, 64);
  if (lane == 0) reds[wid] = s;
  __syncthreads();
  s = reds[0] + reds[1] + reds[2] + reds[3];
  const float inv = 1.f / s;
  short8 o;
#pragma unroll
  for (int j = 0; j < 8; ++j) o[j] = (short)f2bf(e[j] * inv);
  *(short8*)(p + tid * 8) = o;
}

// convert the 4 fp32 512x512 weights to bf16 (contiguous -> wq|wk|wv|wp)
__global__ __launch_bounds__(256) void cvt_w(const float* __restrict__ w0,
                                             const float* __restrict__ w1,
                                             const float* __restrict__ w2,
                                             const float* __restrict__ w3,
                                             u16* __restrict__ out) {
  const int z = blockIdx.y;
  const float* src = (z == 0) ? w0 : (z == 1) ? w1 : (z == 2) ? w2 : w3;
  const int i = blockIdx.x * 256 + threadIdx.x;
  out[(long)z * 262144 + i] = f2bf(src[i]);
}

// concat bq|bk -> bqk[1024]
__global__ __launch_bounds__(256) void cvt_bias(const float* __restrict__ bq,
                                                const float* __restrict__ bk,
                                                float* __restrict__ bqk) {
  const int i = blockIdx.x * 256 + threadIdx.x;
  bqk[i] = (i < 512) ? bq[i] : bk[i - 512];
}

extern "C" void kernel_launch(void* const* d_in, const int* in_sizes, int n_in,
                              void* d_out, int out_size, void* d_ws, size_t ws_size,
                              hipStream_t stream) {
  const float* x = (const float*)d_in[0];
  const float* gs = (const float*)d_in[1];
  const float* gb = (const float*)d_in[2];
  const float* wq = (const float*)d_in[3];
  const float* bq = (const float*)d_in[4];
  const float* wk = (const float*)d_in[5];
  const float* bk = (const float*)d_in[6];
  const float* wv = (const float*)d_in[7];
  const float* bv = (const float*)d_in[8];
  const float* wp = (const float*)d_in[9];
  const float* bp = (const float*)d_in[10];

  char* ws = (char*)d_ws;
  float* stats = (float*)ws;               // 2 KB
  float* bqk = (float*)(ws + 4096);        // 4 KB
  u16* hT = (u16*)(ws + 8192);             // [16384, 512] bf16, 16 MB
  u16* qkT = hT + 8388608;                 // [16384, 1024] bf16, 32 MB (q|k)
  u16* vv = qkT + 16777216;                // [B, 512, 2048] bf16, 16 MB
  u16* S = vv + 8388608;                   // [B, 2048, 2048] bf16, 64 MB
  u16* wb = S + 33554432;                  // wq|wk|wv|wp bf16, 2 MB
  u16* attnT = hT;                         // alias: hT dead after qk + v GEMMs
  float* out = (float*)d_out;

  cvt_w<<<dim3(1024, 4, 1), 256, 0, stream>>>(wq, wk, wv, wp, wb);
  cvt_bias<<<dim3(4), 256, 0, stream>>>(bq, bk, bqk);
  gn_stats<<<dim3(256), 256, 0, stream>>>(x, stats);
  gn_apply_t<<<dim3(32, 8, 8), 256, 0, stream>>>(x, stats, gs, gb, hT);

  // qk: M=16384 (m0=by*256+b*2048), N=1024, K=512; per-b 8m x 8n -> 512 blocks
  gemm12<0><<<dim3(512), 512, 0, stream>>>(
      hT, wb, qkT, bqk, nullptr, 512, 512, 512, 1024, 8, 2048, 0, 0, 0, 0, 0.f);
  // v: M=512, N=2048, K=512; per-b 2m x 16n -> 256 blocks
  gemm12<1><<<dim3(256), 512, 0, stream>>>(
      wb + 524288, hT, vv, bv, nullptr, 512, 512, 512, 2048, 16, 0, 0, 1048576, 1048576, 0, 0.f);
  // S: M=N=2048, K=512; per-b 8m x 16n -> 1024 blocks
  gemm12<2><<<dim3(1024), 512, 0, stream>>>(
      qkT, qkT + 512, S, nullptr, nullptr, 512, 1024, 1024, 2048, 16, 0, 2097152, 2097152,
      4194304, 0, 0.04419417382415922f);
  softmax_rows<<<dim3(16384), 256, 0, stream>>>(S);
  // PV: M=2048, N=512, K=2048; per-b 8m x 4n -> 256 blocks
  gemm12<3><<<dim3(256), 512, 0, stream>>>(
      S, vv, attnT, nullptr, nullptr, 2048, 2048, 2048, 512, 4, 0, 4194304, 1048576,
      1048576, 0, 0.f);
  // proj+residual: M=512, N=2048, K=512; per-b 2m x 16n -> 256 blocks
  gemm12<4><<<dim3(256), 512, 0, stream>>>(
      wb + 786432, attnT, out, bp, x, 512, 512, 512, 2048, 16, 0, 0, 1048576, 1048576,
      1048576, 0.f);
}

// Round 13
// 197.167 us; speedup vs baseline: 1.5916x; 1.5916x over previous
//
#include <hip/hip_runtime.h>
#include <hip/hip_bf16.h>

// AttnBlock: B=8, C=512, N=2048, G=32.
// All GEMMs NT: Out[m][n] = sum_k A[m][k] * Bt[n][k].
// gemm13<MODE>: exact m97 structure (guide-measured 912TF on this chip):
//   128x128 tile, 256 threads (4 waves 2x2, wave 64x64), BK=64, SINGLE-buffered
//   32KB LDS -> ~3 blocks/CU co-residency (implicit wave-level overlap does the
//   hiding, m114), plain __syncthreads() x2 per K-tile, compiler-scheduled
//   ds_read/lgkmcnt (near-optimal per m97 asm dump). NO setprio/sched_barrier/
//   manual vmcnt (all measured null/negative on this structure).
// + T2 XOR swizzle (pre-swizzled global src for global_load_lds, same involution
//   on ds_read) -> 0 bank conflicts (R2-verified).
// + batch->XCD pinning (gid = t*8 + b), by-major in-XCD order (FETCH 74->24MB).

typedef __attribute__((ext_vector_type(8))) short short8;
typedef __attribute__((ext_vector_type(4))) float f32x4;
typedef unsigned short u16;

#define BK 64

__device__ __forceinline__ u16 f2bf(float f) {
  __hip_bfloat16 h = __float2bfloat16(f);
  return __builtin_bit_cast(u16, h);
}
__device__ __forceinline__ float bf2f(u16 u) {
  return __uint_as_float(((unsigned)u) << 16);
}

__device__ __forceinline__ void gload_lds16(const void* g, void* l) {
  __builtin_amdgcn_global_load_lds((const __attribute__((address_space(1))) void*)g,
                                   (__attribute__((address_space(3))) void*)l, 16, 0, 0);
}

// MODE 0: bf16 out = acc + bias[col]   MODE 1: + bias[row]   MODE 2: * scale
// MODE 3: raw bf16                     MODE 4: f32 + bias[row] + resid
// Grid: 1-D, gid = t*8 + b;  t = by*GX + bx;  m0 = by*128 + b*mOffB; n0 = bx*128.
template <int MODE>
__global__ __launch_bounds__(256) void gemm13(
    const u16* __restrict__ A, const u16* __restrict__ Bt, void* __restrict__ OutV,
    const float* __restrict__ bias, const float* __restrict__ resid,
    int K, int lda, int ldb, int ldo, int GX, int mOffB,
    long sA, long sBt, long sOut, long sRes, float scale) {
  __shared__ __align__(16) u16 As[128 * BK];  // 16 KB
  __shared__ __align__(16) u16 Bs[128 * BK];  // 16 KB

  const int gid = blockIdx.x;
  const int b = gid & 7;  // batch == XCD (round-robin dispatch)
  const int t0 = gid >> 3;
  const int bx = t0 % GX;
  const int by = t0 / GX;
  const u16* Ab = A + (long)b * sA;
  const u16* Bb = Bt + (long)b * sBt;
  const int tid = threadIdx.x;
  const int lane = tid & 63;
  const int wid = tid >> 6;
  const int wm = (wid >> 1) * 64;
  const int wn = (wid & 1) * 64;
  const int m0 = by * 128 + b * mOffB;
  const int n0 = bx * 128;
  const int l15 = lane & 15;
  const int lhi = lane >> 4;
  const int sw = l15 & 7;  // swizzle term: 16B-slot ^= (row&7), row ≡ l15 (mod 16)

  f32x4 acc[4][4];
#pragma unroll
  for (int i = 0; i < 4; ++i)
#pragma unroll
    for (int j = 0; j < 4; ++j) acc[i][j] = (f32x4){0.f, 0.f, 0.f, 0.f};

  for (int ks = 0; ks < K; ks += BK) {
    // stage A and Bt tiles (each 128x64 bf16 = 16KB = 1024 16B-chunks), swizzled:
    // chunk c -> row = c>>3, lds slot = c&7; global k-slot = (c&7) ^ (row&7)
#pragma unroll
    for (int i = 0; i < 4; ++i) {
      const int c = tid + i * 256;
      const int row = c >> 3;
      const int gslot = (c & 7) ^ (row & 7);
      gload_lds16(Ab + (long)(m0 + row) * lda + ks + gslot * 8, (void*)(As + c * 8));
    }
#pragma unroll
    for (int i = 0; i < 4; ++i) {
      const int c = tid + i * 256;
      const int row = c >> 3;
      const int gslot = (c & 7) ^ (row & 7);
      gload_lds16(Bb + (long)(n0 + row) * ldb + ks + gslot * 8, (void*)(Bs + c * 8));
    }
    __syncthreads();  // compiler emits vmcnt(0) lgkmcnt(0) drain before barrier

#pragma unroll
    for (int kh = 0; kh < 2; ++kh) {
      short8 af[4], bf[4];
#pragma unroll
      for (int mf = 0; mf < 4; ++mf)
        af[mf] = *(const short8*)(As + (wm + mf * 16 + l15) * BK +
                                  ((kh * 4 + lhi) ^ sw) * 8);
#pragma unroll
      for (int nf = 0; nf < 4; ++nf)
        bf[nf] = *(const short8*)(Bs + (wn + nf * 16 + l15) * BK +
                                  ((kh * 4 + lhi) ^ sw) * 8);
#pragma unroll
      for (int mf = 0; mf < 4; ++mf)
#pragma unroll
        for (int nf = 0; nf < 4; ++nf)
          acc[mf][nf] = __builtin_amdgcn_mfma_f32_16x16x32_bf16(af[mf], bf[nf],
                                                                acc[mf][nf], 0, 0, 0);
    }
    __syncthreads();
  }

  // epilogue: D row=(lane>>4)*4+reg (m), col=lane&15 (n); plain stores (L2-merged)
  const int rbase = m0 + wm + lhi * 4;
  const int cbase = n0 + wn + l15;
#pragma unroll
  for (int mf = 0; mf < 4; ++mf) {
#pragma unroll
    for (int nf = 0; nf < 4; ++nf) {
#pragma unroll
      for (int i = 0; i < 4; ++i) {
        const int row = rbase + mf * 16 + i;
        const int col = cbase + nf * 16;
        const long oidx = (long)b * sOut + (long)row * ldo + col;
        const float v = acc[mf][nf][i];
        if (MODE == 0) {
          ((u16*)OutV)[oidx] = f2bf(v + bias[col]);
        } else if (MODE == 1) {
          ((u16*)OutV)[oidx] = f2bf(v + bias[row]);
        } else if (MODE == 2) {
          ((u16*)OutV)[oidx] = f2bf(v * scale);
        } else if (MODE == 3) {
          ((u16*)OutV)[oidx] = f2bf(v);
        } else {
          const float r = resid[(long)b * sRes + (long)row * ldo + col];
          ((float*)OutV)[oidx] = v + bias[row] + r;
        }
      }
    }
  }
}

// per-(b,g) mean/rstd over contiguous 16*2048 = 32768 floats
__global__ __launch_bounds__(256) void gn_stats(const float* __restrict__ x,
                                                float* __restrict__ stats) {
  const int bg = blockIdx.x;
  const float4* p4 = (const float4*)(x + (long)bg * 32768);
  float s = 0.f, ss = 0.f;
  for (int i = threadIdx.x; i < 8192; i += 256) {
    const float4 u = p4[i];
    s += (u.x + u.y) + (u.z + u.w);
    ss += (u.x * u.x + u.y * u.y) + (u.z * u.z + u.w * u.w);
  }
#pragma unroll
  for (int off = 32; off > 0; off >>= 1) {
    s += __shfl_xor(s, off, 64);
    ss += __shfl_xor(ss, off, 64);
  }
  __shared__ float rs[4], rss[4];
  const int lane = threadIdx.x & 63, wid = threadIdx.x >> 6;
  if (lane == 0) { rs[wid] = s; rss[wid] = ss; }
  __syncthreads();
  if (threadIdx.x == 0) {
    s = rs[0] + rs[1] + rs[2] + rs[3];
    ss = rss[0] + rss[1] + rss[2] + rss[3];
    const float mean = s * (1.f / 32768.f);
    const float var = ss * (1.f / 32768.f) - mean * mean;
    stats[bg * 2] = mean;
    stats[bg * 2 + 1] = rsqrtf(var + 1e-6f);
  }
}

// normalize + affine, write hT[b][n][c] bf16 (64x64 LDS-tiled transpose)
__global__ __launch_bounds__(256) void gn_apply_t(
    const float* __restrict__ x, const float* __restrict__ stats,
    const float* __restrict__ gamma, const float* __restrict__ beta,
    u16* __restrict__ hT) {
  const int b = blockIdx.z, c0 = blockIdx.y * 64, n0 = blockIdx.x * 64;
  __shared__ u16 t[64][72];
  const int tid = threadIdx.x;
  const float* px = x + ((long)b * 512 + c0) * 2048 + n0;
#pragma unroll
  for (int i = 0; i < 4; ++i) {
    const int idx = tid + i * 256;
    const int r = idx >> 4, q4 = (idx & 15) * 4;
    const float4 u = *(const float4*)(px + (long)r * 2048 + q4);
    const int c = c0 + r, g = c >> 4;
    const float mean = stats[(b * 32 + g) * 2];
    const float rstd = stats[(b * 32 + g) * 2 + 1];
    const float ga = gamma[c] * rstd;
    const float be = beta[c] - mean * ga;
    t[r][q4 + 0] = f2bf(u.x * ga + be);
    t[r][q4 + 1] = f2bf(u.y * ga + be);
    t[r][q4 + 2] = f2bf(u.z * ga + be);
    t[r][q4 + 3] = f2bf(u.w * ga + be);
  }
  __syncthreads();
#pragma unroll
  for (int i = 0; i < 2; ++i) {
    const int idx = tid + i * 256;
    const int nr = idx >> 3, cc = (idx & 7) * 8;
    short8 w;
#pragma unroll
    for (int j = 0; j < 8; ++j) w[j] = (short)t[cc + j][nr];
    *(short8*)(hT + ((long)b * 2048 + n0 + nr) * 512 + c0 + cc) = w;
  }
}

// row softmax in place on bf16 S; gid = r*8 + b, row = b*2048 + r (XCD-pinned)
__global__ __launch_bounds__(256) void softmax_rows(u16* __restrict__ S) {
  const int gid = blockIdx.x;
  const long row = (long)(gid & 7) * 2048 + (gid >> 3);
  u16* p = S + row * 2048;
  const int tid = threadIdx.x;
  const int lane = tid & 63, wid = tid >> 6;
  const short8 raw = *(const short8*)(p + tid * 8);
  float v[8];
#pragma unroll
  for (int j = 0; j < 8; ++j) v[j] = bf2f((u16)raw[j]);
  float m = v[0];
#pragma unroll
  for (int j = 1; j < 8; ++j) m = fmaxf(m, v[j]);
#pragma unroll
  for (int off = 32; off > 0; off >>= 1) m = fmaxf(m, __shfl_xor(m, off, 64));
  __shared__ float redm[4], reds[4];
  if (lane == 0) redm[wid] = m;
  __syncthreads();
  m = fmaxf(fmaxf(redm[0], redm[1]), fmaxf(redm[2], redm[3]));
  float e[8];
  float s = 0.f;
#pragma unroll
  for (int j = 0; j < 8; ++j) {
    e[j] = __expf(v[j] - m);
    s += e[j];
  }
#pragma unroll
  for (int off = 32; off > 0; off >>= 1) s += __shfl_xor(s, off, 64);
  if (lane == 0) reds[wid] = s;
  __syncthreads();
  s = reds[0] + reds[1] + reds[2] + reds[3];
  const float inv = 1.f / s;
  short8 o;
#pragma unroll
  for (int j = 0; j < 8; ++j) o[j] = (short)f2bf(e[j] * inv);
  *(short8*)(p + tid * 8) = o;
}

// convert the 4 fp32 512x512 weights to bf16 (contiguous -> wq|wk|wv|wp)
__global__ __launch_bounds__(256) void cvt_w(const float* __restrict__ w0,
                                             const float* __restrict__ w1,
                                             const float* __restrict__ w2,
                                             const float* __restrict__ w3,
                                             u16* __restrict__ out) {
  const int z = blockIdx.y;
  const float* src = (z == 0) ? w0 : (z == 1) ? w1 : (z == 2) ? w2 : w3;
  const int i = blockIdx.x * 256 + threadIdx.x;
  out[(long)z * 262144 + i] = f2bf(src[i]);
}

// concat bq|bk -> bqk[1024]
__global__ __launch_bounds__(256) void cvt_bias(const float* __restrict__ bq,
                                                const float* __restrict__ bk,
                                                float* __restrict__ bqk) {
  const int i = blockIdx.x * 256 + threadIdx.x;
  bqk[i] = (i < 512) ? bq[i] : bk[i - 512];
}

extern "C" void kernel_launch(void* const* d_in, const int* in_sizes, int n_in,
                              void* d_out, int out_size, void* d_ws, size_t ws_size,
                              hipStream_t stream) {
  const float* x = (const float*)d_in[0];
  const float* gs = (const float*)d_in[1];
  const float* gb = (const float*)d_in[2];
  const float* wq = (const float*)d_in[3];
  const float* bq = (const float*)d_in[4];
  const float* wk = (const float*)d_in[5];
  const float* bk = (const float*)d_in[6];
  const float* wv = (const float*)d_in[7];
  const float* bv = (const float*)d_in[8];
  const float* wp = (const float*)d_in[9];
  const float* bp = (const float*)d_in[10];

  char* ws = (char*)d_ws;
  float* stats = (float*)ws;               // 2 KB
  float* bqk = (float*)(ws + 4096);        // 4 KB
  u16* hT = (u16*)(ws + 8192);             // [16384, 512] bf16, 16 MB
  u16* qkT = hT + 8388608;                 // [16384, 1024] bf16, 32 MB (q|k)
  u16* vv = qkT + 16777216;                // [B, 512, 2048] bf16, 16 MB
  u16* S = vv + 8388608;                   // [B, 2048, 2048] bf16, 64 MB
  u16* wb = S + 33554432;                  // wq|wk|wv|wp bf16, 2 MB
  u16* attnT = hT;                         // alias: hT dead after qk + v GEMMs
  float* out = (float*)d_out;

  cvt_w<<<dim3(1024, 4, 1), 256, 0, stream>>>(wq, wk, wv, wp, wb);
  cvt_bias<<<dim3(4), 256, 0, stream>>>(bq, bk, bqk);
  gn_stats<<<dim3(256), 256, 0, stream>>>(x, stats);
  gn_apply_t<<<dim3(32, 8, 8), 256, 0, stream>>>(x, stats, gs, gb, hT);

  // qk: M=16384 (m0=by*128+b*2048), N=1024, K=512; per-b 16m x 8n -> 1024 blocks
  gemm13<0><<<dim3(1024), 256, 0, stream>>>(
      hT, wb, qkT, bqk, nullptr, 512, 512, 512, 1024, 8, 2048, 0, 0, 0, 0, 0.f);
  // v: M=512, N=2048, K=512; per-b 4m x 16n -> 512 blocks
  gemm13<1><<<dim3(512), 256, 0, stream>>>(
      wb + 524288, hT, vv, bv, nullptr, 512, 512, 512, 2048, 16, 0, 0, 1048576, 1048576, 0, 0.f);
  // S: M=N=2048, K=512; per-b 16m x 16n -> 2048 blocks
  gemm13<2><<<dim3(2048), 256, 0, stream>>>(
      qkT, qkT + 512, S, nullptr, nullptr, 512, 1024, 1024, 2048, 16, 0, 2097152, 2097152,
      4194304, 0, 0.04419417382415922f);
  softmax_rows<<<dim3(16384), 256, 0, stream>>>(S);
  // PV: M=2048, N=512, K=2048; per-b 16m x 4n -> 512 blocks
  gemm13<3><<<dim3(512), 256, 0, stream>>>(
      S, vv, attnT, nullptr, nullptr, 2048, 2048, 2048, 512, 4, 0, 4194304, 1048576,
      1048576, 0, 0.f);
  // proj+residual: M=512, N=2048, K=512; per-b 4m x 16n -> 512 blocks
  gemm13<4><<<dim3(512), 256, 0, stream>>>(
      wb + 786432, attnT, out, bp, x, 512, 512, 512, 2048, 16, 0, 0, 1048576, 1048576,
      1048576, 0.f);
}